// Round 6
// baseline (251.477 us; speedup 1.0000x reference)
//
#include <hip/hip_runtime.h>
#include <hip/hip_bf16.h>

#define B_DIM 8192
#define D_DIM 256
#define GRID_GEMM 1024
#define NT 8    // 32-col tiles per block (256 cols per block)

constexpr float INV_T = 14.285714285714286f;   // 1/0.07; also the logsumexp shift M

typedef __bf16 bf16x8 __attribute__((ext_vector_type(8)));
typedef float  f32x16 __attribute__((ext_vector_type(16)));

__device__ inline unsigned short f2bf(float f) {
    union { float f; unsigned u; } x; x.f = f;
    unsigned r = x.u + 0x7fffu + ((x.u >> 16) & 1u);  // RNE
    return (unsigned short)(r >> 16);
}

// Kernel 1: q = normalize(h+r) -> row-major bf16; t = normalize(t) -> bf16 in
// MFMA B-FRAGMENT order: byte ((tile*16+ks)*64 + l)*16 holds
// B[col=tile*32+(l&31)][k=ks*16+(l>>5)*8+j], so the GEMM's B-load is one
// fully-coalesced 1KB global load per wave per ks.
// Block 0 additionally zeroes rowsum/diagsum/ticket.
__global__ __launch_bounds__(256) void norm_kernel(
    const float* __restrict__ h, const float* __restrict__ r,
    const float* __restrict__ t,
    unsigned short* __restrict__ qws, unsigned short* __restrict__ tws,
    float* __restrict__ rowsum, float* __restrict__ diagsum, int* __restrict__ ticket)
{
    if (blockIdx.x == 0) {
        float4* rs4 = (float4*)rowsum;
#pragma unroll
        for (int i = 0; i < 8; ++i)
            rs4[threadIdx.x * 8 + i] = make_float4(0.f, 0.f, 0.f, 0.f);
        if (threadIdx.x == 0) { *diagsum = 0.f; *ticket = 0; }
    }

    const int wave = threadIdx.x >> 6;
    const int lane = threadIdx.x & 63;
    const int wg   = blockIdx.x * 4 + wave;      // 0..4095, 2 rows each

    // --- q rows: row-major bf16 (A-frags load per-block in the gemm) ---
#pragma unroll
    for (int i = 0; i < 2; ++i) {
        const int row = wg * 2 + i;              // 0..8191
        float4 a = ((const float4*)h)[row * 64 + lane];
        float4 b = ((const float4*)r)[row * 64 + lane];
        float4 v = make_float4(a.x + b.x, a.y + b.y, a.z + b.z, a.w + b.w);
        float s = v.x * v.x + v.y * v.y + v.z * v.z + v.w * v.w;
#pragma unroll
        for (int off = 32; off; off >>= 1) s += __shfl_xor(s, off, 64);
        float scale = 1.0f / fmaxf(sqrtf(s), 1e-12f);
        ushort4 o;
        o.x = f2bf(v.x * scale); o.y = f2bf(v.y * scale);
        o.z = f2bf(v.z * scale); o.w = f2bf(v.w * scale);
        ((ushort4*)qws)[row * 64 + lane] = o;
    }

    // --- t rows: store in B-fragment order ---
    // lane holds k in [4*lane, 4*lane+4). Fragment coords:
    // ks = lane>>2, hi = (lane>>1)&1, sub = lane&1;
    // dst 16B-slot = ((row>>5)*16+ks)*64 + hi*32 + (row&31), byte + sub*8.
    {
        const int ks  = lane >> 2;
        const int hi2 = (lane >> 1) & 1;
        const int sub = lane & 1;
#pragma unroll
        for (int i = 0; i < 2; ++i) {
            const int row = wg * 2 + i;
            float4 v = ((const float4*)t)[row * 64 + lane];
            float s = v.x * v.x + v.y * v.y + v.z * v.z + v.w * v.w;
#pragma unroll
            for (int off = 32; off; off >>= 1) s += __shfl_xor(s, off, 64);
            float scale = 1.0f / fmaxf(sqrtf(s), 1e-12f);
            ushort4 o;
            o.x = f2bf(v.x * scale); o.y = f2bf(v.y * scale);
            o.z = f2bf(v.z * scale); o.w = f2bf(v.w * scale);
            size_t slot16 = ((size_t)((row >> 5) * 16 + ks) * 64
                             + (size_t)(hi2 * 32 + (row & 31)));
            *(ushort4*)((unsigned char*)tws + slot16 * 16 + sub * 8) = o;
        }
    }
}

// Kernel 2: A-in-registers streaming GEMM, no LDS in the inner loop, B in
// fragment order (coalesced 1KB loads). Round-5 showed the wall is exposed
// VMEM latency at 2 blocks/CU (grid-limited; VGPR 112 allows 4 waves/SIMD).
// This round: grid 1024 = 32 rb x 32 cc -> 4 blocks/CU resident
// (__launch_bounds__(256,4) caps VGPR at 128; currently 112). 2x the waves
// to hide the per-tile B-load latency; everything else unchanged.
__global__ __launch_bounds__(256, 4) void gemm_lse_kernel(
    const unsigned char* __restrict__ qws, const unsigned char* __restrict__ tws,
    float* __restrict__ rowsum, float* __restrict__ diagsum,
    int* __restrict__ ticket, float* __restrict__ out)
{
    __shared__ float wred[4];
    __shared__ int lastflag;

    const int tid  = threadIdx.x;
    const int lane = tid & 63;
    const int w    = tid >> 6;
    const int l31  = lane & 31;
    const int hi   = lane >> 5;

    const int cc   = blockIdx.x & 31;        // col chunk (fast -> XCD locality)
    const int rb   = blockIdx.x >> 5;        // row block 0..31
    const int row0 = rb * 256 + w * 64;      // this wave's 64 rows (distinct per wave)
    const int col0 = cc * 256;
    const int tile0 = cc * 8;                // first 32-col tile of this chunk

    // ---- A fragments in registers: rows row0..row0+63, full K=256 ----
    // 32x32x16 A layout: m = lane&31, k = ks*16 + hi*8 + j  (16B per frag)
    bf16x8 a[2][16];
    {
        const unsigned char* abase = qws + (size_t)(row0 + l31) * 512 + hi * 16;
#pragma unroll
        for (int rt = 0; rt < 2; ++rt)
#pragma unroll
            for (int ks = 0; ks < 16; ++ks)
                a[rt][ks] = *(const bf16x8*)(abase + rt * (32 * 512) + ks * 32);
    }

    f32x16 rowacc[2] = {};
    float diagacc = 0.f;

    for (int nt = 0; nt < NT; ++nt) {
        // B-fragment base: tile (tile0+nt), lane-indexed, coalesced 1KB/inst.
        const unsigned char* bb = tws + (size_t)(tile0 + nt) * 16384 + lane * 16;

        f32x16 acc0 = {}, acc1 = {};
#pragma unroll
        for (int ks = 0; ks < 16; ++ks) {
            bf16x8 b = *(const bf16x8*)(bb + ks * 1024);
            acc0 = __builtin_amdgcn_mfma_f32_32x32x16_bf16(a[0][ks], b, acc0, 0, 0, 0);
            acc1 = __builtin_amdgcn_mfma_f32_32x32x16_bf16(a[1][ks], b, acc1, 0, 0, 0);
        }

        // hot epilogue: exp-sum only (diag handling below, wave-uniform)
#pragma unroll
        for (int g = 0; g < 16; ++g) {
            rowacc[0][g] += __expf(fmaf(acc0[g], INV_T, -INV_T));
            rowacc[1][g] += __expf(fmaf(acc1[g], INV_T, -INV_T));
        }

        // diagonal tiles: wave-uniform condition, at most 2 of 8 iterations
        const int c0t = col0 + nt * 32;
        if (c0t == row0) {
#pragma unroll
            for (int g = 0; g < 16; ++g) {
                int rm = (g & 3) + 8 * (g >> 2) + 4 * hi;
                if (l31 == rm) diagacc += acc0[g] * INV_T;
            }
        }
        if (c0t == row0 + 32) {
#pragma unroll
            for (int g = 0; g < 16; ++g) {
                int rm = (g & 3) + 8 * (g >> 2) + 4 * hi;
                if (l31 == rm) diagacc += acc1[g] * INV_T;
            }
        }
    }

    // ---- once per block: reduce across the 32 column-lanes, then atomics ----
#pragma unroll
    for (int rt = 0; rt < 2; ++rt)
#pragma unroll
        for (int g = 0; g < 16; ++g) {
            float s = rowacc[rt][g];
            s += __shfl_xor(s, 1, 64);
            s += __shfl_xor(s, 2, 64);
            s += __shfl_xor(s, 4, 64);
            s += __shfl_xor(s, 8, 64);
            s += __shfl_xor(s, 16, 64);
            if (l31 == 0) {
                int grow = row0 + rt * 32 + (g & 3) + 8 * (g >> 2) + 4 * hi;
                atomicAdd(&rowsum[grow], s);
            }
        }

    float dsum = diagacc;
#pragma unroll
    for (int off = 32; off; off >>= 1) dsum += __shfl_xor(dsum, off, 64);
    if (lane == 0 && dsum != 0.f) atomicAdd(diagsum, dsum);

    // ---- ticket: last block computes the loss ----
    __syncthreads();
    if (tid == 0) {
        __threadfence();
        int old = __hip_atomic_fetch_add(ticket, 1, __ATOMIC_ACQ_REL,
                                         __HIP_MEMORY_SCOPE_AGENT);
        lastflag = (old == GRID_GEMM - 1);
    }
    __syncthreads();
    if (!lastflag) return;

    float lsum = 0.f;
    for (int rr = tid; rr < B_DIM; rr += 256) {
        float rs = __hip_atomic_load(&rowsum[rr], __ATOMIC_RELAXED,
                                     __HIP_MEMORY_SCOPE_AGENT);
        lsum += __logf(rs);
    }
#pragma unroll
    for (int off = 32; off; off >>= 1) lsum += __shfl_xor(lsum, off, 64);
    if (lane == 0) wred[w] = lsum;
    __syncthreads();
    if (tid == 0) {
        float ds = __hip_atomic_load(diagsum, __ATOMIC_RELAXED,
                                     __HIP_MEMORY_SCOPE_AGENT);
        float total = wred[0] + wred[1] + wred[2] + wred[3]
                    + (float)B_DIM * INV_T   // + M per row
                    - ds;                    // - positive logits
        out[0] = total / (float)B_DIM;
    }
}

extern "C" void kernel_launch(void* const* d_in, const int* in_sizes, int n_in,
                              void* d_out, int out_size, void* d_ws, size_t ws_size,
                              hipStream_t stream)
{
    const float* h = (const float*)d_in[0];
    const float* r = (const float*)d_in[1];
    const float* t = (const float*)d_in[2];

    unsigned char* ws = (unsigned char*)d_ws;
    unsigned short* qws = (unsigned short*)ws;                        // 4 MB
    unsigned short* tws = (unsigned short*)(ws + 4u * 1024 * 1024);   // 4 MB (frag order)
    float* rowsum  = (float*)(ws + 8u * 1024 * 1024);                 // 32 KB
    float* diagsum = (float*)(ws + 8u * 1024 * 1024 + 32u * 1024);
    int*   ticket  = (int*)  (ws + 8u * 1024 * 1024 + 32u * 1024 + 16);

    norm_kernel<<<1024, 256, 0, stream>>>(h, r, t, qws, tws, rowsum, diagsum, ticket);
    gemm_lse_kernel<<<GRID_GEMM, 256, 0, stream>>>(
        (const unsigned char*)qws, (const unsigned char*)tws,
        rowsum, diagsum, ticket, (float*)d_out);
}

// Round 7
// 166.807 us; speedup vs baseline: 1.5076x; 1.5076x over previous
//
#include <hip/hip_runtime.h>
#include <hip/hip_bf16.h>

#define B_DIM 8192
#define D_DIM 256
#define GRID_GEMM 1024
#define NT 8    // 32-col tiles per block (256 cols per block)

constexpr float INV_T = 14.285714285714286f;   // 1/0.07; also the logsumexp shift M

typedef __bf16 bf16x8 __attribute__((ext_vector_type(8)));
typedef float  f32x16 __attribute__((ext_vector_type(16)));

__device__ inline unsigned short f2bf(float f) {
    union { float f; unsigned u; } x; x.f = f;
    unsigned r = x.u + 0x7fffu + ((x.u >> 16) & 1u);  // RNE
    return (unsigned short)(r >> 16);
}

// Kernel 1: q = normalize(h+r) -> row-major bf16; t = normalize(t) -> bf16 in
// MFMA B-FRAGMENT order: byte ((tile*16+ks)*64 + l)*16 holds
// B[col=tile*32+(l&31)][k=ks*16+(l>>5)*8+j], so the GEMM's B-load is one
// fully-coalesced 1KB global load per wave per ks.
// Block 0 additionally zeroes rowsum/diagsum/ticket.
__global__ __launch_bounds__(256) void norm_kernel(
    const float* __restrict__ h, const float* __restrict__ r,
    const float* __restrict__ t,
    unsigned short* __restrict__ qws, unsigned short* __restrict__ tws,
    float* __restrict__ rowsum, float* __restrict__ diagsum, int* __restrict__ ticket)
{
    if (blockIdx.x == 0) {
        float4* rs4 = (float4*)rowsum;
#pragma unroll
        for (int i = 0; i < 8; ++i)
            rs4[threadIdx.x * 8 + i] = make_float4(0.f, 0.f, 0.f, 0.f);
        if (threadIdx.x == 0) { *diagsum = 0.f; *ticket = 0; }
    }

    const int wave = threadIdx.x >> 6;
    const int lane = threadIdx.x & 63;
    const int wg   = blockIdx.x * 4 + wave;      // 0..4095, 2 rows each

    // --- q rows: row-major bf16 (A-frags load per-block in the gemm) ---
#pragma unroll
    for (int i = 0; i < 2; ++i) {
        const int row = wg * 2 + i;              // 0..8191
        float4 a = ((const float4*)h)[row * 64 + lane];
        float4 b = ((const float4*)r)[row * 64 + lane];
        float4 v = make_float4(a.x + b.x, a.y + b.y, a.z + b.z, a.w + b.w);
        float s = v.x * v.x + v.y * v.y + v.z * v.z + v.w * v.w;
#pragma unroll
        for (int off = 32; off; off >>= 1) s += __shfl_xor(s, off, 64);
        float scale = 1.0f / fmaxf(sqrtf(s), 1e-12f);
        ushort4 o;
        o.x = f2bf(v.x * scale); o.y = f2bf(v.y * scale);
        o.z = f2bf(v.z * scale); o.w = f2bf(v.w * scale);
        ((ushort4*)qws)[row * 64 + lane] = o;
    }

    // --- t rows: store in B-fragment order ---
    // lane holds k in [4*lane, 4*lane+4). Fragment coords:
    // ks = lane>>2, hi = (lane>>1)&1, sub = lane&1;
    // dst 16B-slot = ((row>>5)*16+ks)*64 + hi*32 + (row&31), byte + sub*8.
    {
        const int ks  = lane >> 2;
        const int hi2 = (lane >> 1) & 1;
        const int sub = lane & 1;
#pragma unroll
        for (int i = 0; i < 2; ++i) {
            const int row = wg * 2 + i;
            float4 v = ((const float4*)t)[row * 64 + lane];
            float s = v.x * v.x + v.y * v.y + v.z * v.z + v.w * v.w;
#pragma unroll
            for (int off = 32; off; off >>= 1) s += __shfl_xor(s, off, 64);
            float scale = 1.0f / fmaxf(sqrtf(s), 1e-12f);
            ushort4 o;
            o.x = f2bf(v.x * scale); o.y = f2bf(v.y * scale);
            o.z = f2bf(v.z * scale); o.w = f2bf(v.w * scale);
            size_t slot16 = ((size_t)((row >> 5) * 16 + ks) * 64
                             + (size_t)(hi2 * 32 + (row & 31)));
            *(ushort4*)((unsigned char*)tws + slot16 * 16 + sub * 8) = o;
        }
    }
}

// Kernel 2: A-in-registers streaming GEMM, no LDS in the inner loop, B in
// fragment order (coalesced 1KB loads). Grid 1024 = 32 rb x 32 cc -> 4
// blocks/CU resident (round 6 proved occupancy scales with grid: 38.7%).
// __launch_bounds__ MUST stay (256,2): (256,4) empirically capped VGPR at 64
// and spilled everything (FETCH 18.5->365 MB, 180 us). VGPR 112 <= 128
// already permits 4 waves/SIMD, so the hardware reaches 4 blocks/CU on its
// own once the grid provides them.
__global__ __launch_bounds__(256, 2) void gemm_lse_kernel(
    const unsigned char* __restrict__ qws, const unsigned char* __restrict__ tws,
    float* __restrict__ rowsum, float* __restrict__ diagsum,
    int* __restrict__ ticket, float* __restrict__ out)
{
    __shared__ float wred[4];
    __shared__ int lastflag;

    const int tid  = threadIdx.x;
    const int lane = tid & 63;
    const int w    = tid >> 6;
    const int l31  = lane & 31;
    const int hi   = lane >> 5;

    const int cc   = blockIdx.x & 31;        // col chunk (fast -> XCD locality)
    const int rb   = blockIdx.x >> 5;        // row block 0..31
    const int row0 = rb * 256 + w * 64;      // this wave's 64 rows (distinct per wave)
    const int col0 = cc * 256;
    const int tile0 = cc * 8;                // first 32-col tile of this chunk

    // ---- A fragments in registers: rows row0..row0+63, full K=256 ----
    // 32x32x16 A layout: m = lane&31, k = ks*16 + hi*8 + j  (16B per frag)
    bf16x8 a[2][16];
    {
        const unsigned char* abase = qws + (size_t)(row0 + l31) * 512 + hi * 16;
#pragma unroll
        for (int rt = 0; rt < 2; ++rt)
#pragma unroll
            for (int ks = 0; ks < 16; ++ks)
                a[rt][ks] = *(const bf16x8*)(abase + rt * (32 * 512) + ks * 32);
    }

    f32x16 rowacc[2] = {};
    float diagacc = 0.f;

    for (int nt = 0; nt < NT; ++nt) {
        // B-fragment base: tile (tile0+nt), lane-indexed, coalesced 1KB/inst.
        const unsigned char* bb = tws + (size_t)(tile0 + nt) * 16384 + lane * 16;

        f32x16 acc0 = {}, acc1 = {};
#pragma unroll
        for (int ks = 0; ks < 16; ++ks) {
            bf16x8 b = *(const bf16x8*)(bb + ks * 1024);
            acc0 = __builtin_amdgcn_mfma_f32_32x32x16_bf16(a[0][ks], b, acc0, 0, 0, 0);
            acc1 = __builtin_amdgcn_mfma_f32_32x32x16_bf16(a[1][ks], b, acc1, 0, 0, 0);
        }

        // hot epilogue: exp-sum only (diag handling below, wave-uniform)
#pragma unroll
        for (int g = 0; g < 16; ++g) {
            rowacc[0][g] += __expf(fmaf(acc0[g], INV_T, -INV_T));
            rowacc[1][g] += __expf(fmaf(acc1[g], INV_T, -INV_T));
        }

        // diagonal tiles: wave-uniform condition, at most 2 of 8 iterations
        const int c0t = col0 + nt * 32;
        if (c0t == row0) {
#pragma unroll
            for (int g = 0; g < 16; ++g) {
                int rm = (g & 3) + 8 * (g >> 2) + 4 * hi;
                if (l31 == rm) diagacc += acc0[g] * INV_T;
            }
        }
        if (c0t == row0 + 32) {
#pragma unroll
            for (int g = 0; g < 16; ++g) {
                int rm = (g & 3) + 8 * (g >> 2) + 4 * hi;
                if (l31 == rm) diagacc += acc1[g] * INV_T;
            }
        }
    }

    // ---- once per block: reduce across the 32 column-lanes, then atomics ----
#pragma unroll
    for (int rt = 0; rt < 2; ++rt)
#pragma unroll
        for (int g = 0; g < 16; ++g) {
            float s = rowacc[rt][g];
            s += __shfl_xor(s, 1, 64);
            s += __shfl_xor(s, 2, 64);
            s += __shfl_xor(s, 4, 64);
            s += __shfl_xor(s, 8, 64);
            s += __shfl_xor(s, 16, 64);
            if (l31 == 0) {
                int grow = row0 + rt * 32 + (g & 3) + 8 * (g >> 2) + 4 * hi;
                atomicAdd(&rowsum[grow], s);
            }
        }

    float dsum = diagacc;
#pragma unroll
    for (int off = 32; off; off >>= 1) dsum += __shfl_xor(dsum, off, 64);
    if (lane == 0 && dsum != 0.f) atomicAdd(diagsum, dsum);

    // ---- ticket: last block computes the loss ----
    __syncthreads();
    if (tid == 0) {
        __threadfence();
        int old = __hip_atomic_fetch_add(ticket, 1, __ATOMIC_ACQ_REL,
                                         __HIP_MEMORY_SCOPE_AGENT);
        lastflag = (old == GRID_GEMM - 1);
    }
    __syncthreads();
    if (!lastflag) return;

    float lsum = 0.f;
    for (int rr = tid; rr < B_DIM; rr += 256) {
        float rs = __hip_atomic_load(&rowsum[rr], __ATOMIC_RELAXED,
                                     __HIP_MEMORY_SCOPE_AGENT);
        lsum += __logf(rs);
    }
#pragma unroll
    for (int off = 32; off; off >>= 1) lsum += __shfl_xor(lsum, off, 64);
    if (lane == 0) wred[w] = lsum;
    __syncthreads();
    if (tid == 0) {
        float ds = __hip_atomic_load(diagsum, __ATOMIC_RELAXED,
                                     __HIP_MEMORY_SCOPE_AGENT);
        float total = wred[0] + wred[1] + wred[2] + wred[3]
                    + (float)B_DIM * INV_T   // + M per row
                    - ds;                    // - positive logits
        out[0] = total / (float)B_DIM;
    }
}

extern "C" void kernel_launch(void* const* d_in, const int* in_sizes, int n_in,
                              void* d_out, int out_size, void* d_ws, size_t ws_size,
                              hipStream_t stream)
{
    const float* h = (const float*)d_in[0];
    const float* r = (const float*)d_in[1];
    const float* t = (const float*)d_in[2];

    unsigned char* ws = (unsigned char*)d_ws;
    unsigned short* qws = (unsigned short*)ws;                        // 4 MB
    unsigned short* tws = (unsigned short*)(ws + 4u * 1024 * 1024);   // 4 MB (frag order)
    float* rowsum  = (float*)(ws + 8u * 1024 * 1024);                 // 32 KB
    float* diagsum = (float*)(ws + 8u * 1024 * 1024 + 32u * 1024);
    int*   ticket  = (int*)  (ws + 8u * 1024 * 1024 + 32u * 1024 + 16);

    norm_kernel<<<1024, 256, 0, stream>>>(h, r, t, qws, tws, rowsum, diagsum, ticket);
    gemm_lse_kernel<<<GRID_GEMM, 256, 0, stream>>>(
        (const unsigned char*)qws, (const unsigned char*)tws,
        rowsum, diagsum, ticket, (float*)d_out);
}

// Round 8
// 132.360 us; speedup vs baseline: 1.8999x; 1.2602x over previous
//
#include <hip/hip_runtime.h>
#include <hip/hip_bf16.h>

#define B_DIM 8192
#define D_DIM 256
#define GRID_GEMM 512
#define NT 16   // 32-col tiles per block (512 cols per block)

constexpr float INV_T = 14.285714285714286f;   // 1/0.07; also the logsumexp shift M

typedef __bf16 bf16x8 __attribute__((ext_vector_type(8)));
typedef float  f32x16 __attribute__((ext_vector_type(16)));

#define GLOBAL_U32(p) ((const __attribute__((address_space(1))) unsigned int*)(p))
#define LDS_U32(p)    ((__attribute__((address_space(3))) unsigned int*)(p))

// s_waitcnt imm (gfx9): vm[3:0]=bits3:0, exp=bits6:4, lgkm=bits11:8, vm[5:4]=bits15:14
// vmcnt(8), expcnt/lgkmcnt = no-wait:
#define WAITCNT_VM8 0x0F78

__device__ inline unsigned short f2bf(float f) {
    union { float f; unsigned u; } x; x.f = f;
    unsigned r = x.u + 0x7fffu + ((x.u >> 16) & 1u);  // RNE
    return (unsigned short)(r >> 16);
}

// Kernel 1: q = normalize(h+r), t = normalize(t), BOTH stored in MFMA
// FRAGMENT order: 16B-slot ((row>>5)*16 + ks)*64 + hi*32 + (row&31) holds
// row's k = ks*16 + hi*8 + j. This makes the GEMM's A-prologue and the
// LDS staging/reads fully linear (verified transform, R5/R7).
// Block 0 additionally zeroes rowsum/diagsum/ticket.
__global__ __launch_bounds__(256) void norm_kernel(
    const float* __restrict__ h, const float* __restrict__ r,
    const float* __restrict__ t,
    unsigned short* __restrict__ qws, unsigned short* __restrict__ tws,
    float* __restrict__ rowsum, float* __restrict__ diagsum, int* __restrict__ ticket)
{
    if (blockIdx.x == 0) {
        float4* rs4 = (float4*)rowsum;
#pragma unroll
        for (int i = 0; i < 8; ++i)
            rs4[threadIdx.x * 8 + i] = make_float4(0.f, 0.f, 0.f, 0.f);
        if (threadIdx.x == 0) { *diagsum = 0.f; *ticket = 0; }
    }

    const int wave = threadIdx.x >> 6;
    const int lane = threadIdx.x & 63;
    const int wg   = blockIdx.x * 4 + wave;      // 0..4095, 2 rows each

    // fragment store coords for this lane (k = 4*lane + j):
    const int ks  = lane >> 2;
    const int hi2 = (lane >> 1) & 1;
    const int sub = lane & 1;

#pragma unroll
    for (int i = 0; i < 2; ++i) {
        const int row = wg * 2 + i;              // 0..8191
        // ---- q = normalize(h+r) ----
        {
            float4 a = ((const float4*)h)[row * 64 + lane];
            float4 b = ((const float4*)r)[row * 64 + lane];
            float4 v = make_float4(a.x + b.x, a.y + b.y, a.z + b.z, a.w + b.w);
            float s = v.x * v.x + v.y * v.y + v.z * v.z + v.w * v.w;
#pragma unroll
            for (int off = 32; off; off >>= 1) s += __shfl_xor(s, off, 64);
            float scale = 1.0f / fmaxf(sqrtf(s), 1e-12f);
            ushort4 o;
            o.x = f2bf(v.x * scale); o.y = f2bf(v.y * scale);
            o.z = f2bf(v.z * scale); o.w = f2bf(v.w * scale);
            size_t slot16 = ((size_t)((row >> 5) * 16 + ks) * 64
                             + (size_t)(hi2 * 32 + (row & 31)));
            *(ushort4*)((unsigned char*)qws + slot16 * 16 + sub * 8) = o;
        }
        // ---- t = normalize(t) ----
        {
            float4 v = ((const float4*)t)[row * 64 + lane];
            float s = v.x * v.x + v.y * v.y + v.z * v.z + v.w * v.w;
#pragma unroll
            for (int off = 32; off; off >>= 1) s += __shfl_xor(s, off, 64);
            float scale = 1.0f / fmaxf(sqrtf(s), 1e-12f);
            ushort4 o;
            o.x = f2bf(v.x * scale); o.y = f2bf(v.y * scale);
            o.z = f2bf(v.z * scale); o.w = f2bf(v.w * scale);
            size_t slot16 = ((size_t)((row >> 5) * 16 + ks) * 64
                             + (size_t)(hi2 * 32 + (row & 31)));
            *(ushort4*)((unsigned char*)tws + slot16 * 16 + sub * 8) = o;
        }
    }
}

// Kernel 2: the verified R0 pipeline (4x16KB LDS ring, prefetch distance 2,
// s_waitcnt vmcnt(8) + raw barrier, NO vmcnt(0) drain) with fragment-order
// workspaces: STAGE is a trivial linear copy (global_load_lds linear-dest
// constraint satisfied with no swizzle), the LDS B-read is lane*16+ks*1024
// (linear, conflict-free, immediate-offset ds_read_b128), and the A-prologue
// is fully-coalesced 1KB loads. Removes R0's 2.1M conflict cycles + swizzle
// VALU without touching the proven sync structure.
__global__ __launch_bounds__(256, 2) void gemm_lse_kernel(
    const unsigned char* __restrict__ qws, const unsigned char* __restrict__ tws,
    float* __restrict__ rowsum, float* __restrict__ diagsum,
    int* __restrict__ ticket, float* __restrict__ out)
{
    __shared__ __align__(16) unsigned char ldsB[4][32 * 512];   // 64 KB
    __shared__ float wred[4];
    __shared__ int lastflag;

    const int tid  = threadIdx.x;
    const int lane = tid & 63;
    const int w    = tid >> 6;
    const int l31  = lane & 31;
    const int hi   = lane >> 5;

    const int cc   = blockIdx.x & 15;        // col chunk (fast -> XCD locality)
    const int rb   = blockIdx.x >> 4;        // row block 0..31
    const int row0 = rb * 256 + w * 64;      // this wave's 64 rows (distinct per wave)
    const int col0 = cc * 512;
    const int tile0 = cc * 16;               // first 32-col tile of this chunk

    // stage tile snt (16 KB, fragment-order = linear) into buffer bufi
#define STAGE(snt, bufi)                                                     \
    {                                                                        \
        const unsigned char* gs = tws + (size_t)(tile0 + (snt)) * 16384;     \
        _Pragma("unroll")                                                    \
        for (int it = 0; it < 4; ++it)                                       \
            __builtin_amdgcn_global_load_lds(                                \
                GLOBAL_U32(gs + (it * 256 + tid) * 16),                      \
                LDS_U32(&ldsB[bufi][(it * 256 + tid) * 16]), 16, 0, 0);      \
    }

    // prologue: tiles 0 and 1 in flight before the A-fragment loads
    STAGE(0, 0);
    STAGE(1, 1);

    // ---- A fragments in registers: rows row0..row0+63, full K=256 ----
    // frag-order qws: byte = row0*512 + rt*16384 + ks*1024 + lane*16
    // -> row = row0 + rt*32 + l31, k = ks*16 + hi*8 + j  (same as R0)
    bf16x8 a[2][16];
    {
        const unsigned char* abase = qws + (size_t)row0 * 512 + lane * 16;
#pragma unroll
        for (int rt = 0; rt < 2; ++rt)
#pragma unroll
            for (int ks = 0; ks < 16; ++ks)
                a[rt][ks] = *(const bf16x8*)(abase + rt * 16384 + ks * 1024);
    }

    f32x16 rowacc[2] = {};
    float diagacc = 0.f;

    for (int nt = 0; nt < NT; ++nt) {
        // prefetch distance 2; tail: dummy re-stage of tile NT-1 into the
        // (dead) target buffer keeps the in-flight count uniform at 8.
        const int snt = (nt + 2 < NT) ? nt + 2 : NT - 1;
        STAGE(snt, (nt + 2) & 3);

        // wait for tile nt's loads only (tiles nt+1, nt+2 = 8 insts stay in
        // flight), then a raw barrier -- NO vmcnt(0) drain.
        __builtin_amdgcn_s_waitcnt(WAITCNT_VM8);
        __builtin_amdgcn_s_barrier();

        const unsigned char* bbuf = ldsB[nt & 3] + lane * 16;
        f32x16 acc0 = {}, acc1 = {};
#pragma unroll
        for (int ks = 0; ks < 16; ++ks) {
            bf16x8 b = *(const bf16x8*)(bbuf + ks * 1024);
            acc0 = __builtin_amdgcn_mfma_f32_32x32x16_bf16(a[0][ks], b, acc0, 0, 0, 0);
            acc1 = __builtin_amdgcn_mfma_f32_32x32x16_bf16(a[1][ks], b, acc1, 0, 0, 0);
        }

        // hot epilogue: exp-sum only (diag handling hoisted below)
#pragma unroll
        for (int g = 0; g < 16; ++g) {
            rowacc[0][g] += __expf(fmaf(acc0[g], INV_T, -INV_T));
            rowacc[1][g] += __expf(fmaf(acc1[g], INV_T, -INV_T));
        }

        // diagonal tiles: wave-uniform condition, at most 2 of 16 iterations
        const int c0t = col0 + nt * 32;
        if (c0t == row0) {
#pragma unroll
            for (int g = 0; g < 16; ++g) {
                int rm = (g & 3) + 8 * (g >> 2) + 4 * hi;
                if (l31 == rm) diagacc += acc0[g] * INV_T;
            }
        }
        if (c0t == row0 + 32) {
#pragma unroll
            for (int g = 0; g < 16; ++g) {
                int rm = (g & 3) + 8 * (g >> 2) + 4 * hi;
                if (l31 == rm) diagacc += acc1[g] * INV_T;
            }
        }
    }

    // ---- once per block: reduce across the 32 column-lanes, then atomics ----
#pragma unroll
    for (int rt = 0; rt < 2; ++rt)
#pragma unroll
        for (int g = 0; g < 16; ++g) {
            float s = rowacc[rt][g];
            s += __shfl_xor(s, 1, 64);
            s += __shfl_xor(s, 2, 64);
            s += __shfl_xor(s, 4, 64);
            s += __shfl_xor(s, 8, 64);
            s += __shfl_xor(s, 16, 64);
            if (l31 == 0) {
                int grow = row0 + rt * 32 + (g & 3) + 8 * (g >> 2) + 4 * hi;
                atomicAdd(&rowsum[grow], s);
            }
        }

    float dsum = diagacc;
#pragma unroll
    for (int off = 32; off; off >>= 1) dsum += __shfl_xor(dsum, off, 64);
    if (lane == 0 && dsum != 0.f) atomicAdd(diagsum, dsum);

    // ---- ticket: last block computes the loss ----
    __syncthreads();
    if (tid == 0) {
        __threadfence();
        int old = __hip_atomic_fetch_add(ticket, 1, __ATOMIC_ACQ_REL,
                                         __HIP_MEMORY_SCOPE_AGENT);
        lastflag = (old == GRID_GEMM - 1);
    }
    __syncthreads();
    if (!lastflag) return;

    float lsum = 0.f;
    for (int rr = tid; rr < B_DIM; rr += 256) {
        float rs = __hip_atomic_load(&rowsum[rr], __ATOMIC_RELAXED,
                                     __HIP_MEMORY_SCOPE_AGENT);
        lsum += __logf(rs);
    }
#pragma unroll
    for (int off = 32; off; off >>= 1) lsum += __shfl_xor(lsum, off, 64);
    if (lane == 0) wred[w] = lsum;
    __syncthreads();
    if (tid == 0) {
        float ds = __hip_atomic_load(diagsum, __ATOMIC_RELAXED,
                                     __HIP_MEMORY_SCOPE_AGENT);
        float total = wred[0] + wred[1] + wred[2] + wred[3]
                    + (float)B_DIM * INV_T   // + M per row
                    - ds;                    // - positive logits
        out[0] = total / (float)B_DIM;
    }
}

extern "C" void kernel_launch(void* const* d_in, const int* in_sizes, int n_in,
                              void* d_out, int out_size, void* d_ws, size_t ws_size,
                              hipStream_t stream)
{
    const float* h = (const float*)d_in[0];
    const float* r = (const float*)d_in[1];
    const float* t = (const float*)d_in[2];

    unsigned char* ws = (unsigned char*)d_ws;
    unsigned short* qws = (unsigned short*)ws;                        // 4 MB (frag order)
    unsigned short* tws = (unsigned short*)(ws + 4u * 1024 * 1024);   // 4 MB (frag order)
    float* rowsum  = (float*)(ws + 8u * 1024 * 1024);                 // 32 KB
    float* diagsum = (float*)(ws + 8u * 1024 * 1024 + 32u * 1024);
    int*   ticket  = (int*)  (ws + 8u * 1024 * 1024 + 32u * 1024 + 16);

    norm_kernel<<<1024, 256, 0, stream>>>(h, r, t, qws, tws, rowsum, diagsum, ticket);
    gemm_lse_kernel<<<GRID_GEMM, 256, 0, stream>>>(
        (const unsigned char*)qws, (const unsigned char*)tws,
        rowsum, diagsum, ticket, (float*)d_out);
}